// Round 4
// baseline (4469.415 us; speedup 1.0000x reference)
//
#include <hip/hip_runtime.h>
#include <hip/hip_bf16.h>
#include <cstdint>
#include <cstddef>

#define NN  100000
#define EE  1600000
#define NE2 1700000

#define OUT_X2    3200000   // NN*32 (start of edge_index region, f32 elements)
#define OUT_ALPHA 6600000   // NN*32 + 2*NE2 (start of alpha region)

__device__ __forceinline__ float lrelu(float v) { return v >= 0.f ? v : 0.2f * v; }

// ---------------------------------------------------------------------------
// GEMM1: h1 = x @ W1^T   ([NN,128] = [NN,128] @ [128,128]^T)
// block 256 thr, 32 rows/block. cg = t&31 -> cols 4cg..4cg+3,
// rg = t>>5 -> rows 4rg..4rg+3. Plain LDS tiles (2-way bank alias = free).
// ---------------------------------------------------------------------------
__global__ __launch_bounds__(256) void k_gemm1(
    const float* __restrict__ x, const float* __restrict__ W1,
    float* __restrict__ h1)
{
  __shared__ float Wt[128 * 128];   // Wt[f*128 + c] = W1[c*128 + f]
  __shared__ float xs[32 * 128];    // xs[r*128 + f]
  const int t = threadIdx.x;
  const int row0 = blockIdx.x * 32;

  {
    const float4* W4 = (const float4*)W1;
    #pragma unroll
    for (int i = 0; i < 16; ++i) {
      int idx4 = t * 16 + i;          // [0,4096)
      int c = idx4 >> 5, f4 = idx4 & 31;
      float4 v = W4[idx4];
      Wt[(4 * f4 + 0) * 128 + c] = v.x;
      Wt[(4 * f4 + 1) * 128 + c] = v.y;
      Wt[(4 * f4 + 2) * 128 + c] = v.z;
      Wt[(4 * f4 + 3) * 128 + c] = v.w;
    }
  }
  #pragma unroll
  for (int i = 0; i < 16; ++i) {      // 32 rows x 128 = 4096 = 16*256
    int idx = i * 256 + t;
    int r = idx >> 7, f = idx & 127;
    int grow = row0 + r;
    xs[r * 128 + f] = (grow < NN) ? x[(size_t)grow * 128 + f] : 0.f;
  }
  __syncthreads();

  const int cg = t & 31;
  const int rg = t >> 5;
  float acc[4][4];
  #pragma unroll
  for (int j = 0; j < 4; ++j)
    #pragma unroll
    for (int k = 0; k < 4; ++k) acc[j][k] = 0.f;

  const float4* Wt4 = (const float4*)Wt;
  #pragma unroll 4
  for (int f = 0; f < 128; ++f) {
    float4 wv = Wt4[f * 32 + cg];
    #pragma unroll
    for (int j = 0; j < 4; ++j) {
      float xv = xs[(4 * rg + j) * 128 + f];
      acc[j][0] += xv * wv.x; acc[j][1] += xv * wv.y;
      acc[j][2] += xv * wv.z; acc[j][3] += xv * wv.w;
    }
  }

  #pragma unroll
  for (int j = 0; j < 4; ++j) {
    int grow = row0 + 4 * rg + j;
    if (grow < NN)
      *(float4*)&h1[(size_t)grow * 128 + 4 * cg] =
          make_float4(acc[j][0], acc[j][1], acc[j][2], acc[j][3]);
  }
}

// ---------------------------------------------------------------------------
// attention logits layer 1: als[n,h] = sum_c h1[n,h*16+c]*a_src[h,c]; same ald
// ---------------------------------------------------------------------------
__global__ __launch_bounds__(256) void k_att1(
    const float* __restrict__ h1, const float* __restrict__ a_src,
    const float* __restrict__ a_dst,
    float* __restrict__ als, float* __restrict__ ald)
{
  int tid = blockIdx.x * 256 + threadIdx.x;
  int n = tid >> 3, h = tid & 7;
  const float4* hp = (const float4*)&h1[(size_t)n * 128 + h * 16];
  const float4* sp = (const float4*)&a_src[h * 16];
  const float4* dp = (const float4*)&a_dst[h * 16];
  float s = 0.f, d = 0.f;
  #pragma unroll
  for (int j = 0; j < 4; ++j) {
    float4 hv = hp[j], sv = sp[j], dv = dp[j];
    s += hv.x * sv.x + hv.y * sv.y + hv.z * sv.z + hv.w * sv.w;
    d += hv.x * dv.x + hv.y * dv.y + hv.z * dv.z + hv.w * dv.w;
  }
  als[(size_t)n * 8 + h] = s;
  ald[(size_t)n * 8 + h] = d;
}

// ---------------------------------------------------------------------------
// layer-1 softmax denominator (shift-free: softmax is shift-invariant;
// e in ~[-3, +12] after LeakyReLU -> exp() f32-safe)
// ---------------------------------------------------------------------------
__global__ __launch_bounds__(256) void k_esum1(
    const int* __restrict__ ei, const float* __restrict__ als,
    const float* __restrict__ ald, float* __restrict__ s1)
{
  int i = blockIdx.x * 256 + threadIdx.x;
  if (i >= NE2) return;
  int src, dst;
  if (i < EE) { src = ei[i]; dst = ei[EE + i]; } else { src = dst = i - EE; }
  const float* A = als + (size_t)src * 8;
  const float* D = ald + (size_t)dst * 8;
  float4 a0 = *(const float4*)A, a1 = *(const float4*)(A + 4);
  float4 d0 = *(const float4*)D, d1 = *(const float4*)(D + 4);
  float* S = s1 + (size_t)dst * 8;
  atomicAdd(S + 0, __expf(lrelu(a0.x + d0.x)));
  atomicAdd(S + 1, __expf(lrelu(a0.y + d0.y)));
  atomicAdd(S + 2, __expf(lrelu(a0.z + d0.z)));
  atomicAdd(S + 3, __expf(lrelu(a0.w + d0.w)));
  atomicAdd(S + 4, __expf(lrelu(a1.x + d1.x)));
  atomicAdd(S + 5, __expf(lrelu(a1.y + d1.y)));
  atomicAdd(S + 6, __expf(lrelu(a1.z + d1.z)));
  atomicAdd(S + 7, __expf(lrelu(a1.w + d1.w)));
}

// ---------------------------------------------------------------------------
// layer-1 aggregation: acc1[dst][c] += alpha[e][h(c)] * h1[src][c]
// 32 lanes per edge, float4 per lane
// ---------------------------------------------------------------------------
__global__ __launch_bounds__(256) void k_agg1(
    const int* __restrict__ ei, const float* __restrict__ als,
    const float* __restrict__ ald, const float* __restrict__ s1,
    const float* __restrict__ h1, float* __restrict__ acc1)
{
  int tid = blockIdx.x * 256 + threadIdx.x;
  int e = tid >> 5, q = tid & 31;
  if (e >= NE2) return;
  int src, dst;
  if (e < EE) { src = ei[e]; dst = ei[EE + e]; } else { src = dst = e - EE; }
  int h = q >> 2;
  float ev = lrelu(als[(size_t)src * 8 + h] + ald[(size_t)dst * 8 + h]);
  float alpha = __expf(ev) / (s1[(size_t)dst * 8 + h] + 1e-16f);
  float4 hv = *(const float4*)&h1[(size_t)src * 128 + 4 * q];
  float* o = &acc1[(size_t)dst * 128 + 4 * q];
  atomicAdd(o + 0, alpha * hv.x);
  atomicAdd(o + 1, alpha * hv.y);
  atomicAdd(o + 2, alpha * hv.z);
  atomicAdd(o + 3, alpha * hv.w);
}

// ---------------------------------------------------------------------------
// GEMM2: h2 = relu(acc1 + b1) @ W2^T   ([NN,32])
// ---------------------------------------------------------------------------
__global__ __launch_bounds__(256) void k_gemm2(
    const float* __restrict__ acc1, const float* __restrict__ b1,
    const float* __restrict__ W2, float* __restrict__ h2)
{
  __shared__ float Wt[128 * 32];    // Wt[f*32 + c] = W2[c*128 + f]
  __shared__ float xs[64 * 128];    // xs[r*128 + f]
  const int t = threadIdx.x;
  const int row0 = blockIdx.x * 64;

  {
    const float4* W4 = (const float4*)W2;
    #pragma unroll
    for (int i = 0; i < 4; ++i) {
      int idx4 = t * 4 + i;           // [0,1024)
      int c = idx4 >> 5, f4 = idx4 & 31;
      float4 v = W4[idx4];
      Wt[(4 * f4 + 0) * 32 + c] = v.x;
      Wt[(4 * f4 + 1) * 32 + c] = v.y;
      Wt[(4 * f4 + 2) * 32 + c] = v.z;
      Wt[(4 * f4 + 3) * 32 + c] = v.w;
    }
  }
  #pragma unroll
  for (int i = 0; i < 32; ++i) {      // 64 rows x 128 = 8192 = 32*256
    int idx = i * 256 + t;
    int r = idx >> 7, f = idx & 127;
    int grow = row0 + r;
    xs[r * 128 + f] =
        (grow < NN) ? fmaxf(acc1[(size_t)grow * 128 + f] + b1[f], 0.f) : 0.f;
  }
  __syncthreads();

  const int c = t & 31;
  const int rg = t >> 5;              // rows 8rg..8rg+7
  float acc[8];
  #pragma unroll
  for (int j = 0; j < 8; ++j) acc[j] = 0.f;

  #pragma unroll 4
  for (int f = 0; f < 128; ++f) {
    float wv = Wt[f * 32 + c];
    #pragma unroll
    for (int j = 0; j < 8; ++j)
      acc[j] += xs[(8 * rg + j) * 128 + f] * wv;
  }

  #pragma unroll
  for (int j = 0; j < 8; ++j) {
    int grow = row0 + 8 * rg + j;
    if (grow < NN) h2[(size_t)grow * 32 + c] = acc[j];
  }
}

// ---------------------------------------------------------------------------
// attention logits layer 2 (heads=1, K=32)
// ---------------------------------------------------------------------------
__global__ __launch_bounds__(256) void k_att2(
    const float* __restrict__ h2, const float* __restrict__ a_src,
    const float* __restrict__ a_dst,
    float* __restrict__ als, float* __restrict__ ald)
{
  int n = blockIdx.x * 256 + threadIdx.x;
  if (n >= NN) return;
  float s = 0.f, d = 0.f;
  #pragma unroll
  for (int j = 0; j < 8; ++j) {
    float4 hv = *(const float4*)&h2[(size_t)n * 32 + 4 * j];
    float4 sv = *(const float4*)&a_src[4 * j];
    float4 dv = *(const float4*)&a_dst[4 * j];
    s += hv.x * sv.x + hv.y * sv.y + hv.z * sv.z + hv.w * sv.w;
    d += hv.x * dv.x + hv.y * dv.y + hv.z * dv.z + hv.w * dv.w;
  }
  als[n] = s;
  ald[n] = d;
}

// ---------------------------------------------------------------------------
// layer-2 softmax denominator
// ---------------------------------------------------------------------------
__global__ __launch_bounds__(256) void k_esum2(
    const int* __restrict__ ei, const float* __restrict__ als,
    const float* __restrict__ ald, float* __restrict__ s2)
{
  int i = blockIdx.x * 256 + threadIdx.x;
  if (i >= NE2) return;
  int src, dst;
  if (i < EE) { src = ei[i]; dst = ei[EE + i]; } else { src = dst = i - EE; }
  atomicAdd(&s2[dst], __expf(lrelu(als[src] + ald[dst])));
}

// ---------------------------------------------------------------------------
// layer-2 aggregation + alpha output (f32). 8 lanes per edge
// ---------------------------------------------------------------------------
__global__ __launch_bounds__(256) void k_agg2(
    const int* __restrict__ ei, const float* __restrict__ als,
    const float* __restrict__ ald, const float* __restrict__ s2,
    const float* __restrict__ h2, float* __restrict__ acc2,
    float* __restrict__ outAlpha)
{
  int tid = blockIdx.x * 256 + threadIdx.x;
  int e = tid >> 3, q = tid & 7;
  if (e >= NE2) return;
  int src, dst;
  if (e < EE) { src = ei[e]; dst = ei[EE + e]; } else { src = dst = e - EE; }
  float ev = lrelu(als[src] + ald[dst]);
  float alpha = __expf(ev) / (s2[dst] + 1e-16f);
  if (q == 0) outAlpha[e] = alpha;
  float4 hv = *(const float4*)&h2[(size_t)src * 32 + 4 * q];
  float* o = &acc2[(size_t)dst * 32 + 4 * q];
  atomicAdd(o + 0, alpha * hv.x);
  atomicAdd(o + 1, alpha * hv.y);
  atomicAdd(o + 2, alpha * hv.z);
  atomicAdd(o + 3, alpha * hv.w);
}

// ---------------------------------------------------------------------------
// finalize (f32 out): x2 = acc2 + b2 ; edge_index_new as float
// ---------------------------------------------------------------------------
__global__ __launch_bounds__(256) void k_final(
    const float* __restrict__ acc2, const float* __restrict__ b2,
    const int* __restrict__ ei, float* __restrict__ out)
{
  int i = blockIdx.x * 256 + threadIdx.x;
  if (i < OUT_X2) {
    out[i] = acc2[i] + b2[i & 31];
  } else {
    int j = i - OUT_X2;
    if (j < 2 * NE2) {
      int r = (j >= NE2) ? 1 : 0;     // 0 = src row, 1 = dst row
      int k = j - r * NE2;
      int v = (k < EE) ? ei[r * EE + k] : (k - EE);
      out[i] = (float)v;
    }
  }
}

// ---------------------------------------------------------------------------
extern "C" void kernel_launch(void* const* d_in, const int* in_sizes, int n_in,
                              void* d_out, int out_size, void* d_ws, size_t ws_size,
                              hipStream_t stream)
{
  const float* x   = (const float*)d_in[0];
  const int*   ei  = (const int*)d_in[1];
  const float* W1  = (const float*)d_in[2];
  const float* as1 = (const float*)d_in[3];
  const float* ad1 = (const float*)d_in[4];
  const float* b1  = (const float*)d_in[5];
  const float* W2  = (const float*)d_in[6];
  const float* as2 = (const float*)d_in[7];
  const float* ad2 = (const float*)d_in[8];
  const float* b2  = (const float*)d_in[9];
  float* out = (float*)d_out;          // f32 output buffer (outputs are f32/int32)

  if (ws_size < 138800000) return;     // need ~132 MB of scratch

  char* ws = (char*)d_ws;
  float* h1   = (float*)(ws + 0);          // [NN][128] 51.2 MB
  float* acc1 = (float*)(ws + 51200000);   // [NN][128] 51.2 MB
  float* als1 = (float*)(ws + 102400000);  // [NN][8]
  float* ald1 = (float*)(ws + 105600000);  // [NN][8]
  float* s1   = (float*)(ws + 108800000);  // [NN][8]
  float* h2   = (float*)(ws + 112000000);  // [NN][32]
  float* acc2 = (float*)(ws + 124800000);  // [NN][32]
  float* als2 = (float*)(ws + 137600000);  // [NN]
  float* ald2 = (float*)(ws + 138000000);  // [NN]
  float* s2   = (float*)(ws + 138400000);  // [NN]

  hipMemsetAsync(acc1, 0, 51200000, stream);
  hipMemsetAsync(s1,   0, 3200000,  stream);
  hipMemsetAsync(acc2, 0, 12800000, stream);
  hipMemsetAsync(s2,   0, 400000,   stream);

  k_gemm1<<<(NN + 31) / 32, 256, 0, stream>>>(x, W1, h1);
  k_att1 <<<(NN * 8) / 256, 256, 0, stream>>>(h1, as1, ad1, als1, ald1);
  k_esum1<<<(NE2 + 255) / 256, 256, 0, stream>>>(ei, als1, ald1, s1);
  k_agg1 <<<(NE2 * 32) / 256, 256, 0, stream>>>(ei, als1, ald1, s1, h1, acc1);
  k_gemm2<<<(NN + 63) / 64, 256, 0, stream>>>(acc1, b1, W2, h2);
  k_att2 <<<(NN + 255) / 256, 256, 0, stream>>>(h2, as2, ad2, als2, ald2);
  k_esum2<<<(NE2 + 255) / 256, 256, 0, stream>>>(ei, als2, ald2, s2);
  k_agg2 <<<(NE2 * 8) / 256, 256, 0, stream>>>(ei, als2, ald2, s2, h2, acc2, out + OUT_ALPHA);
  k_final<<<(OUT_ALPHA + 255) / 256, 256, 0, stream>>>(acc2, b2, ei, out);
}

// Round 5
// 672.505 us; speedup vs baseline: 6.6459x; 6.6459x over previous
//
#include <hip/hip_runtime.h>
#include <hip/hip_bf16.h>
#include <cstdint>
#include <cstddef>

#define NN  100000
#define EE  1600000
#define NE2 1700000
#define NBLK 391            // (NN+255)/256

#define OUT_X2    3200000   // NN*32 (start of edge_index region, f32 elements)
#define OUT_ALPHA 6600000   // NN*32 + 2*NE2 (start of alpha region)

__device__ __forceinline__ float lrelu(float v) { return v >= 0.f ? v : 0.2f * v; }

// ---------------------------------------------------------------------------
// GEMM1: h1 = x @ W1^T   ([NN,128] = [NN,128] @ [128,128]^T)
// ---------------------------------------------------------------------------
__global__ __launch_bounds__(256) void k_gemm1(
    const float* __restrict__ x, const float* __restrict__ W1,
    float* __restrict__ h1)
{
  __shared__ float Wt[128 * 128];   // Wt[f*128 + c] = W1[c*128 + f]
  __shared__ float xs[32 * 128];    // xs[r*128 + f]
  const int t = threadIdx.x;
  const int row0 = blockIdx.x * 32;

  {
    const float4* W4 = (const float4*)W1;
    #pragma unroll
    for (int i = 0; i < 16; ++i) {
      int idx4 = t * 16 + i;          // [0,4096)
      int c = idx4 >> 5, f4 = idx4 & 31;
      float4 v = W4[idx4];
      Wt[(4 * f4 + 0) * 128 + c] = v.x;
      Wt[(4 * f4 + 1) * 128 + c] = v.y;
      Wt[(4 * f4 + 2) * 128 + c] = v.z;
      Wt[(4 * f4 + 3) * 128 + c] = v.w;
    }
  }
  #pragma unroll
  for (int i = 0; i < 16; ++i) {      // 32 rows x 128 = 4096 = 16*256
    int idx = i * 256 + t;
    int r = idx >> 7, f = idx & 127;
    int grow = row0 + r;
    xs[r * 128 + f] = (grow < NN) ? x[(size_t)grow * 128 + f] : 0.f;
  }
  __syncthreads();

  const int cg = t & 31;
  const int rg = t >> 5;
  float acc[4][4];
  #pragma unroll
  for (int j = 0; j < 4; ++j)
    #pragma unroll
    for (int k = 0; k < 4; ++k) acc[j][k] = 0.f;

  const float4* Wt4 = (const float4*)Wt;
  #pragma unroll 4
  for (int f = 0; f < 128; ++f) {
    float4 wv = Wt4[f * 32 + cg];
    #pragma unroll
    for (int j = 0; j < 4; ++j) {
      float xv = xs[(4 * rg + j) * 128 + f];
      acc[j][0] += xv * wv.x; acc[j][1] += xv * wv.y;
      acc[j][2] += xv * wv.z; acc[j][3] += xv * wv.w;
    }
  }

  #pragma unroll
  for (int j = 0; j < 4; ++j) {
    int grow = row0 + 4 * rg + j;
    if (grow < NN)
      *(float4*)&h1[(size_t)grow * 128 + 4 * cg] =
          make_float4(acc[j][0], acc[j][1], acc[j][2], acc[j][3]);
  }
}

// ---------------------------------------------------------------------------
// attention logits layer 1
// ---------------------------------------------------------------------------
__global__ __launch_bounds__(256) void k_att1(
    const float* __restrict__ h1, const float* __restrict__ a_src,
    const float* __restrict__ a_dst,
    float* __restrict__ als, float* __restrict__ ald)
{
  int tid = blockIdx.x * 256 + threadIdx.x;
  int n = tid >> 3, h = tid & 7;
  const float4* hp = (const float4*)&h1[(size_t)n * 128 + h * 16];
  const float4* sp = (const float4*)&a_src[h * 16];
  const float4* dp = (const float4*)&a_dst[h * 16];
  float s = 0.f, d = 0.f;
  #pragma unroll
  for (int j = 0; j < 4; ++j) {
    float4 hv = hp[j], sv = sp[j], dv = dp[j];
    s += hv.x * sv.x + hv.y * sv.y + hv.z * sv.z + hv.w * sv.w;
    d += hv.x * dv.x + hv.y * dv.y + hv.z * dv.z + hv.w * dv.w;
  }
  als[(size_t)n * 8 + h] = s;
  ald[(size_t)n * 8 + h] = d;
}

// ---------------------------------------------------------------------------
// CSR build: degree histogram -> block scan -> global scan -> offsets+scatter
// ---------------------------------------------------------------------------
__global__ __launch_bounds__(256) void k_deg(
    const int* __restrict__ ei, int* __restrict__ deg)
{
  int i = blockIdx.x * 256 + threadIdx.x;
  if (i >= NE2) return;
  int dst = (i < EE) ? ei[EE + i] : (i - EE);
  atomicAdd(&deg[dst], 1);
}

__global__ __launch_bounds__(256) void k_scan1(
    const int* __restrict__ deg, int* __restrict__ bscan,
    int* __restrict__ partial)
{
  __shared__ int tmp[256];
  int t = threadIdx.x;
  int i = blockIdx.x * 256 + t;
  int v = (i < NN) ? deg[i] : 0;
  tmp[t] = v;
  __syncthreads();
  #pragma unroll
  for (int off = 1; off < 256; off <<= 1) {
    int add = (t >= off) ? tmp[t - off] : 0;
    __syncthreads();
    tmp[t] += add;
    __syncthreads();
  }
  if (i < NN) bscan[i] = tmp[t] - v;            // block-local exclusive
  if (t == 255) partial[blockIdx.x] = tmp[255]; // block total
}

__global__ __launch_bounds__(512) void k_scan2(
    const int* __restrict__ partial, int* __restrict__ pscan)
{
  __shared__ int tmp[512];
  int t = threadIdx.x;
  int v = (t < NBLK) ? partial[t] : 0;
  tmp[t] = v;
  __syncthreads();
  #pragma unroll
  for (int off = 1; off < 512; off <<= 1) {
    int add = (t >= off) ? tmp[t - off] : 0;
    __syncthreads();
    tmp[t] += add;
    __syncthreads();
  }
  if (t < NBLK) pscan[t] = tmp[t] - v;          // exclusive
}

__global__ __launch_bounds__(256) void k_scan3(
    const int* __restrict__ bscan, const int* __restrict__ pscan,
    int* __restrict__ base, int* __restrict__ cursor)
{
  int i = blockIdx.x * 256 + threadIdx.x;
  if (i < NN) {
    int b = bscan[i] + pscan[i >> 8];
    base[i] = b;
    cursor[i] = b;
  }
  if (i == 0) base[NN] = NE2;
}

__global__ __launch_bounds__(256) void k_scatter(
    const int* __restrict__ ei, int* __restrict__ cursor,
    int* __restrict__ csr_src)
{
  int i = blockIdx.x * 256 + threadIdx.x;
  if (i >= NE2) return;
  int src, dst;
  if (i < EE) { src = ei[i]; dst = ei[EE + i]; } else { src = dst = i - EE; }
  int pos = atomicAdd(&cursor[dst], 1);
  csr_src[pos] = src;
}

// ---------------------------------------------------------------------------
// layer-1 fused softmax+aggregate (atomic-free): one wave per node.
// out[n][c] = (sum_e w_e * h1[src_e][c]) / (sum_e w_e),  w_e = exp(lrelu(...))
// lane handles channels {2*lane, 2*lane+1}; head h = lane>>3.
// (max-shift skipped: softmax is shift-invariant; e = O(10) -> f32-safe)
// ---------------------------------------------------------------------------
__global__ __launch_bounds__(256) void k_node1(
    const int* __restrict__ base, const int* __restrict__ csr_src,
    const float* __restrict__ als, const float* __restrict__ ald,
    const float* __restrict__ h1, float* __restrict__ out)
{
  int wid = (blockIdx.x * 256 + threadIdx.x) >> 6;   // node; grid exact
  int lane = threadIdx.x & 63;
  int h = lane >> 3;
  float ad = ald[(size_t)wid * 8 + h];
  int s0 = base[wid], s1 = base[wid + 1];
  float ax = 0.f, ay = 0.f, sw = 0.f;
  for (int i = s0; i < s1; ++i) {
    int src = csr_src[i];                            // wave-uniform broadcast
    float w = __expf(lrelu(als[(size_t)src * 8 + h] + ad));
    float2 hv = *(const float2*)&h1[(size_t)src * 128 + 2 * lane];
    ax += w * hv.x; ay += w * hv.y; sw += w;
  }
  float inv = 1.f / (sw + 1e-16f);
  *(float2*)&out[(size_t)wid * 128 + 2 * lane] = make_float2(ax * inv, ay * inv);
}

// ---------------------------------------------------------------------------
// GEMM2: h2 = relu(acc1 + b1) @ W2^T   ([NN,32])
// ---------------------------------------------------------------------------
__global__ __launch_bounds__(256) void k_gemm2(
    const float* __restrict__ acc1, const float* __restrict__ b1,
    const float* __restrict__ W2, float* __restrict__ h2)
{
  __shared__ float Wt[128 * 32];    // Wt[f*32 + c] = W2[c*128 + f]
  __shared__ float xs[64 * 128];    // xs[r*128 + f]
  const int t = threadIdx.x;
  const int row0 = blockIdx.x * 64;

  {
    const float4* W4 = (const float4*)W2;
    #pragma unroll
    for (int i = 0; i < 4; ++i) {
      int idx4 = t * 4 + i;           // [0,1024)
      int c = idx4 >> 5, f4 = idx4 & 31;
      float4 v = W4[idx4];
      Wt[(4 * f4 + 0) * 32 + c] = v.x;
      Wt[(4 * f4 + 1) * 32 + c] = v.y;
      Wt[(4 * f4 + 2) * 32 + c] = v.z;
      Wt[(4 * f4 + 3) * 32 + c] = v.w;
    }
  }
  #pragma unroll
  for (int i = 0; i < 32; ++i) {      // 64 rows x 128 = 8192 = 32*256
    int idx = i * 256 + t;
    int r = idx >> 7, f = idx & 127;
    int grow = row0 + r;
    xs[r * 128 + f] =
        (grow < NN) ? fmaxf(acc1[(size_t)grow * 128 + f] + b1[f], 0.f) : 0.f;
  }
  __syncthreads();

  const int c = t & 31;
  const int rg = t >> 5;              // rows 8rg..8rg+7
  float acc[8];
  #pragma unroll
  for (int j = 0; j < 8; ++j) acc[j] = 0.f;

  #pragma unroll 4
  for (int f = 0; f < 128; ++f) {
    float wv = Wt[f * 32 + c];
    #pragma unroll
    for (int j = 0; j < 8; ++j)
      acc[j] += xs[(8 * rg + j) * 128 + f] * wv;
  }

  #pragma unroll
  for (int j = 0; j < 8; ++j) {
    int grow = row0 + 8 * rg + j;
    if (grow < NN) h2[(size_t)grow * 32 + c] = acc[j];
  }
}

// ---------------------------------------------------------------------------
// attention logits layer 2 (heads=1, K=32)
// ---------------------------------------------------------------------------
__global__ __launch_bounds__(256) void k_att2(
    const float* __restrict__ h2, const float* __restrict__ a_src,
    const float* __restrict__ a_dst,
    float* __restrict__ als, float* __restrict__ ald)
{
  int n = blockIdx.x * 256 + threadIdx.x;
  if (n >= NN) return;
  float s = 0.f, d = 0.f;
  #pragma unroll
  for (int j = 0; j < 8; ++j) {
    float4 hv = *(const float4*)&h2[(size_t)n * 32 + 4 * j];
    float4 sv = *(const float4*)&a_src[4 * j];
    float4 dv = *(const float4*)&a_dst[4 * j];
    s += hv.x * sv.x + hv.y * sv.y + hv.z * sv.z + hv.w * sv.w;
    d += hv.x * dv.x + hv.y * dv.y + hv.z * dv.z + hv.w * dv.w;
  }
  als[n] = s;
  ald[n] = d;
}

// ---------------------------------------------------------------------------
// layer-2 fused softmax+aggregate: half-wave (32 lanes) per node.
// Writes x2 (= agg + b2) directly into d_out; stores denominator s2.
// ---------------------------------------------------------------------------
__global__ __launch_bounds__(256) void k_node2(
    const int* __restrict__ base, const int* __restrict__ csr_src,
    const float* __restrict__ als, const float* __restrict__ ald,
    const float* __restrict__ h2, const float* __restrict__ b2,
    float* __restrict__ out_x2, float* __restrict__ s2)
{
  int node = (blockIdx.x * 256 + threadIdx.x) >> 5;  // grid exact
  int lane = threadIdx.x & 31;
  float ad = ald[node];
  int s0 = base[node], s1 = base[node + 1];
  float acc = 0.f, sw = 0.f;
  for (int i = s0; i < s1; ++i) {
    int src = csr_src[i];
    float w = __expf(lrelu(als[src] + ad));
    acc += w * h2[(size_t)src * 32 + lane];
    sw += w;
  }
  out_x2[(size_t)node * 32 + lane] = acc / (sw + 1e-16f) + b2[lane];
  if (lane == 0) s2[node] = sw;
}

// ---------------------------------------------------------------------------
// per-edge alpha output (layer 2) — pure gather, no atomics
// ---------------------------------------------------------------------------
__global__ __launch_bounds__(256) void k_alpha2(
    const int* __restrict__ ei, const float* __restrict__ als,
    const float* __restrict__ ald, const float* __restrict__ s2,
    float* __restrict__ outAlpha)
{
  int e = blockIdx.x * 256 + threadIdx.x;
  if (e >= NE2) return;
  int src, dst;
  if (e < EE) { src = ei[e]; dst = ei[EE + e]; } else { src = dst = e - EE; }
  float w = __expf(lrelu(als[src] + ald[dst]));
  outAlpha[e] = w / (s2[dst] + 1e-16f);
}

// ---------------------------------------------------------------------------
// edge_index_new as float into out[OUT_X2 .. OUT_X2+2*NE2)
// ---------------------------------------------------------------------------
__global__ __launch_bounds__(256) void k_edges(
    const int* __restrict__ ei, float* __restrict__ out)
{
  int j = blockIdx.x * 256 + threadIdx.x;
  if (j >= 2 * NE2) return;
  int r = (j >= NE2) ? 1 : 0;         // 0 = src row, 1 = dst row
  int k = j - r * NE2;
  int v = (k < EE) ? ei[r * EE + k] : (k - EE);
  out[OUT_X2 + j] = (float)v;
}

// ---------------------------------------------------------------------------
extern "C" void kernel_launch(void* const* d_in, const int* in_sizes, int n_in,
                              void* d_out, int out_size, void* d_ws, size_t ws_size,
                              hipStream_t stream)
{
  const float* x   = (const float*)d_in[0];
  const int*   ei  = (const int*)d_in[1];
  const float* W1  = (const float*)d_in[2];
  const float* as1 = (const float*)d_in[3];
  const float* ad1 = (const float*)d_in[4];
  const float* b1  = (const float*)d_in[5];
  const float* W2  = (const float*)d_in[6];
  const float* as2 = (const float*)d_in[7];
  const float* ad2 = (const float*)d_in[8];
  const float* b2  = (const float*)d_in[9];
  float* out = (float*)d_out;          // outputs are f32/int32 -> f32 buffer

  if (ws_size < 138800000) return;

  char* ws = (char*)d_ws;
  float* h1    = (float*)(ws + 0);            // [NN][128] 51.2 MB
  float* acc1  = (float*)(ws + 51200000);     // [NN][128] 51.2 MB
  float* als1  = (float*)(ws + 102400000);    // [NN][8]
  float* ald1  = (float*)(ws + 105600000);    // [NN][8]
  float* h2    = (float*)(ws + 108800000);    // [NN][32] 12.8 MB
  float* als2  = (float*)(ws + 121600000);    // [NN]
  float* ald2  = (float*)(ws + 122000000);    // [NN]
  float* s2    = (float*)(ws + 122400000);    // [NN]
  int*   deg   = (int*)(ws + 122800000);      // [NN]
  int*   bscan = (int*)(ws + 123200000);      // [NN]
  int*   part  = (int*)(ws + 123600000);      // [NBLK] (4 KB slot)
  int*   pscan = (int*)(ws + 123604096);      // [NBLK] (4 KB slot)
  int*   base  = (int*)(ws + 123608192);      // [NN+1]
  int*   cur   = (int*)(ws + 124008208);      // [NN]
  int*   csr   = (int*)(ws + 124408208);      // [NE2] 6.8 MB -> ends 131.2 MB

  hipMemsetAsync(deg, 0, 400000, stream);

  // CSR build (shared by both layers)
  k_deg    <<<(NE2 + 255) / 256, 256, 0, stream>>>(ei, deg);
  k_scan1  <<<NBLK, 256, 0, stream>>>(deg, bscan, part);
  k_scan2  <<<1, 512, 0, stream>>>(part, pscan);
  k_scan3  <<<NBLK, 256, 0, stream>>>(bscan, pscan, base, cur);
  k_scatter<<<(NE2 + 255) / 256, 256, 0, stream>>>(ei, cur, csr);

  // layer 1
  k_gemm1<<<(NN + 31) / 32, 256, 0, stream>>>(x, W1, h1);
  k_att1 <<<(NN * 8) / 256, 256, 0, stream>>>(h1, as1, ad1, als1, ald1);
  k_node1<<<(NN * 64) / 256, 256, 0, stream>>>(base, csr, als1, ald1, h1, acc1);

  // layer 2
  k_gemm2<<<(NN + 63) / 64, 256, 0, stream>>>(acc1, b1, W2, h2);
  k_att2 <<<(NN + 255) / 256, 256, 0, stream>>>(h2, as2, ad2, als2, ald2);
  k_node2<<<(NN * 32) / 256, 256, 0, stream>>>(base, csr, als2, ald2, h2, b2, out, s2);

  // edge outputs
  k_alpha2<<<(NE2 + 255) / 256, 256, 0, stream>>>(ei, als2, ald2, s2, out + OUT_ALPHA);
  k_edges <<<(2 * NE2 + 255) / 256, 256, 0, stream>>>(ei, out);
}